// Round 11
// baseline (951.565 us; speedup 1.0000x reference)
//
#include <hip/hip_runtime.h>
#include <math.h>
#include <stdint.h>

typedef unsigned short u16;
typedef float f32x4 __attribute__((ext_vector_type(4)));
typedef short bf16x8 __attribute__((ext_vector_type(8)));

#define NVIEW 6

// ---------- helpers ----------
__device__ __forceinline__ u16 f2bf(float f){
  unsigned u = __float_as_uint(f);
  u += 0x7FFFu + ((u >> 16) & 1u);
  return (u16)(u >> 16);
}
__device__ __forceinline__ float bf2f(u16 h){
  return __uint_as_float(((unsigned)h) << 16);
}
__device__ __forceinline__ float fsig(float x){
  x = fminf(fmaxf(x, -30.f), 30.f);
  return 1.0f / (1.0f + __expf(-x));
}
__device__ __forceinline__ float ftanh(float x){
  x = fminf(fmaxf(x, -15.f), 15.f);
  float e = __expf(2.0f * x);
  return (e - 1.0f) / (e + 1.0f);
}
__device__ __forceinline__ float gelu_exact(float v){
  float x  = v * 0.70710678118654752f;
  float ax = fabsf(x);
  float t  = 1.0f / fmaf(0.3275911f, ax, 1.0f);
  float p  = t * fmaf(t, fmaf(t, fmaf(t, fmaf(t, 1.061405429f, -1.453152027f),
                                      1.421413741f), -0.284496736f), 0.254829592f);
  float er = copysignf(1.0f - p * __expf(-ax * ax), x);
  return 0.5f * v * (1.0f + er);
}
__device__ __forceinline__ void gload16(const u16* g, u16* l){
  __builtin_amdgcn_global_load_lds((const __attribute__((address_space(1))) unsigned int*)g,
                                   (__attribute__((address_space(3))) unsigned int*)l,
                                   16, 0, 0);
}

// ---------- setup kernels ----------
__global__ void k_cvt(const float* __restrict__ in, u16* __restrict__ out, long n4){
  long i = (long)blockIdx.x * blockDim.x + threadIdx.x;
  long stride = (long)gridDim.x * blockDim.x;
  for (; i < n4; i += stride){
    const float4 v = ((const float4*)in)[i];
    ushort4 o;
    o.x = f2bf(v.x); o.y = f2bf(v.y); o.z = f2bf(v.z); o.w = f2bf(v.w);
    ((ushort4*)out)[i] = o;
  }
}

// Wl[l][4u+q][k] = (k<256 ? Wih[l][q*256+u][k] : Whh[l][q*256+u][k-256]) as bf16
__global__ void k_build_wl(const float* __restrict__ Wih, const float* __restrict__ Whh,
                           u16* __restrict__ Wl){
  int idx = blockIdx.x * 256 + threadIdx.x;
  int l   = idx >> 19;
  int rem = idx & 524287;
  int ro  = rem >> 9;
  int k   = rem & 511;
  int u = ro >> 2, q = ro & 3;
  int ri = q * 256 + u;
  float v = (k < 256) ? Wih[(l * 1024 + ri) * 256 + k]
                      : Whh[(l * 1024 + ri) * 256 + (k - 256)];
  Wl[idx] = f2bf(v);
}

__global__ void k_build_bias(const float* __restrict__ bih, const float* __restrict__ bhh,
                             float* __restrict__ biasL){
  int idx = blockIdx.x * 256 + threadIdx.x;
  if (idx < 3072){
    int l = idx >> 10; int ro = idx & 1023;
    int u = ro >> 2, q = ro & 3;
    int ri = q * 256 + u;
    biasL[idx] = bih[l * 1024 + ri] + bhh[l * 1024 + ri];
  }
}

// =====================================================================
// Deep-ring 128x128 GEMM (r7-proven) for G1/G2.
// =====================================================================
template<int EPI>
__global__ __launch_bounds__(256, 2)
void gemm_dr(const u16* __restrict__ A0, long sA0,
             const u16* __restrict__ Bm, long sB,
             int N, int K, int NBn,
             const float* __restrict__ bias,
             const float* __restrict__ resid,
             u16* __restrict__ outb)
{
  __shared__ __align__(16) u16 lA[5 * 4096];
  __shared__ __align__(16) u16 lB[5 * 4096];

  const int tid  = threadIdx.x;
  const int lane = tid & 63;
  const int wid  = tid >> 6;
  const int wm = wid >> 1, wn = wid & 1;
  const int l15 = lane & 15, lk = lane >> 4;

  const int nwg = gridDim.x;
  const int qx  = nwg >> 3;
  const int bb  = blockIdx.x;
  const int swz = (bb & 7) * qx + (bb >> 3);
  const long m0 = (long)(swz / NBn) * 128;
  const int  n0 = (swz % NBn) * 128;
  const int  NT = K >> 5;

  const int rA0 = tid >> 2;
  const int cA  = tid & 3;
  const int slog = (((rA0 & 1) << 2) | cA) ^ ((rA0 >> 1) & 7);
  const int srow = (rA0 & ~1) | (slog >> 2);
  const int scol = (slog & 3) << 3;
  const int ldst = rA0 * 32 + cA * 8;

  auto STAGE = [&](int slot, int t){
    const int kb = t << 5;
    const int so = slot * 4096;
    #pragma unroll
    for (int c = 0; c < 2; ++c){
      const int r  = c * 64 + srow;
      gload16(A0 + (m0 + r) * sA0 + (kb + scol), &lA[so + c * 2048 + ldst]);
    }
    #pragma unroll
    for (int c = 0; c < 2; ++c){
      const int r  = c * 64 + srow;
      gload16(Bm + (long)(n0 + r) * sB + (kb + scol), &lB[so + c * 2048 + ldst]);
    }
  };

  f32x4 acc[4][4];
  #pragma unroll
  for (int i = 0; i < 4; ++i)
    #pragma unroll
    for (int j = 0; j < 4; ++j)
      acc[i][j] = (f32x4){0.f, 0.f, 0.f, 0.f};

  const int spA = (((l15 & 1) << 2) | lk) ^ (l15 >> 1);
  const int rdA = (wm * 32 + (l15 >> 1)) * 64 + spA * 8;
  const int rdB = (wn * 32 + (l15 >> 1)) * 64 + spA * 8;

  auto COMPUTE = [&](int slot){
    const int so = slot * 4096;
    bf16x8 af[4], bq[4];
    #pragma unroll
    for (int mf = 0; mf < 4; ++mf)
      af[mf] = *(const bf16x8*)&lA[so + rdA + mf * 512];
    #pragma unroll
    for (int nf = 0; nf < 4; ++nf)
      bq[nf] = *(const bf16x8*)&lB[so + rdB + nf * 512];
    #pragma unroll
    for (int mf = 0; mf < 4; ++mf)
      #pragma unroll
      for (int nf = 0; nf < 4; ++nf)
        acc[mf][nf] = __builtin_amdgcn_mfma_f32_16x16x32_bf16(af[mf], bq[nf], acc[mf][nf], 0, 0, 0);
  };

  STAGE(0, 0); STAGE(1, 1); STAGE(2, 2); STAGE(3, 3);

  int sr = 0, sw = 4;
  for (int t = 0; t + 4 <= NT; ++t){
    asm volatile("s_waitcnt vmcnt(12)" ::: "memory");
    asm volatile("s_barrier" ::: "memory");
    if (t + 4 < NT){ STAGE(sw, t + 4); }
    COMPUTE(sr);
    sr = (sr == 4) ? 0 : sr + 1;
    sw = (sw == 4) ? 0 : sw + 1;
  }
  asm volatile("s_waitcnt vmcnt(8)" ::: "memory");
  asm volatile("s_barrier" ::: "memory");
  COMPUTE(sr); sr = (sr == 4) ? 0 : sr + 1;
  asm volatile("s_waitcnt vmcnt(4)" ::: "memory");
  asm volatile("s_barrier" ::: "memory");
  COMPUTE(sr); sr = (sr == 4) ? 0 : sr + 1;
  asm volatile("s_waitcnt vmcnt(0)" ::: "memory");
  asm volatile("s_barrier" ::: "memory");
  COMPUTE(sr);

  #pragma unroll
  for (int mf = 0; mf < 4; ++mf){
    #pragma unroll
    for (int nf = 0; nf < 4; ++nf){
      int  n    = n0 + wn * 64 + nf * 16 + l15;
      long mrow = m0 + wm * 64 + mf * 16 + lk * 4;
      float bz = bias[n];
      #pragma unroll
      for (int r = 0; r < 4; ++r){
        float v = acc[mf][nf][r] + bz;
        long off = (mrow + r) * N + n;
        if (EPI == 0) v = gelu_exact(v) + resid[off];
        outb[off] = f2bf(v);
      }
    }
  }
}

// =====================================================================
// Fused persistent LSTM: 3 layers x 6 timesteps in ONE kernel.
// 256 blocks x 256 thr (4 waves, 1/SIMD); block owns 32 batch rows.
// Recurrence is ROW-LOCAL -> no grid sync ever needed.
//  - A-LDS [32 rows][512 k] (x-half k<256, h-half k>=256), 16B slots
//    swizzled s_phys = s ^ (row&7) (uniform-bank floor). h written in
//    place by the cell update = next step's operand; x re-staged per t.
//  - B (Wl gate-rows) streamed from L2 via 3-slot ring of [512][32]
//    half-tiles (r7 inverse-perm swizzle verbatim), counted vmcnt(8) +
//    raw barriers, 2 halves of lookahead. B source depends only on
//    (layer, kt, hf) -> flat stream g in [0,576).
//  - c in registers (static-indexed cc[2][2][8]); quad-transpose cell
//    verbatim from the verified EPI2 epilogue.
//  - per (l,t): h bounced LDS->global (layer l+1 reads it as x; L3-hot).
// =====================================================================
__global__ __launch_bounds__(256, 1)
void k_lstm(const u16* __restrict__ X0, const u16* __restrict__ Wl,
            const float* __restrict__ biasL,
            u16* __restrict__ HA, u16* __restrict__ HB)
{
  __shared__ __align__(16) u16 lA[16384];      // [32][512] swizzled
  __shared__ __align__(16) u16 lB[3 * 16384];  // ring of [512][32]

  const int tid  = threadIdx.x;
  const int lane = tid & 63;
  const int wv   = tid >> 6;            // wave 0..3 -> gate cols wv*128
  const int l15  = lane & 15, lk = lane >> 4;
  const int ax   = l15 & 7;             // A-read xor key (row&7)
  const int spB  = (((l15 & 1) << 2) | lk) ^ (l15 >> 1);
  const int a    = lane & 3;
  const int qb   = lane & ~3;
  const long R   = (long)blockIdx.x * 32;

  // B staging mapping (r7 inverse-perm, verbatim)
  const int rB0 = tid >> 2;
  const int cB  = tid & 3;
  const int slogB = (((rB0 & 1) << 2) | cB) ^ ((rB0 >> 1) & 7);
  const int srowB = (rB0 & ~1) | (slogB >> 2);
  const int scolB = (slogB & 3) << 3;
  const int ldstB = rB0 * 32 + cB * 8;

  auto STB = [&](int g){
    if (g < 576){
      const int lw  = g / 192;
      const int hcl = g % 32;
      const int ring = g % 3;
      const u16* src = Wl + (long)lw * 524288 + (long)(hcl & 1) * 262144 + (hcl >> 1) * 32;
      u16* dst = &lB[ring * 16384];
      #pragma unroll
      for (int ch = 0; ch < 8; ++ch)
        gload16(src + (long)(ch * 64 + srowB) * 512 + scolB, dst + ch * 2048 + ldstB);
    }
  };

  // x/h bounce thread mapping: row xr_, 64B chunk xcb
  const int xr_ = tid >> 3;
  const int xcb = tid & 7;
  const int xk  = xr_ & 7;

  f32x4 acc[2][2][8];
  float cc[2][2][8];
  float bv[2][8];

  int g = 0;
  STB(0); STB(1);

  for (int l = 0; l < 3; ++l){
    const u16* xsrc = (l == 0) ? X0 : ((l == 1) ? HA : HB);
    u16* hdst = (l == 1) ? HB : HA;
    #pragma unroll
    for (int hf = 0; hf < 2; ++hf)
      #pragma unroll
      for (int nt = 0; nt < 8; ++nt){
        bv[hf][nt] = biasL[l * 1024 + hf * 512 + wv * 128 + nt * 16 + l15];
        #pragma unroll
        for (int mt = 0; mt < 2; ++mt) cc[mt][hf][nt] = 0.f;
      }
    __syncthreads();                        // prior layer's reads done
    {                                        // zero h-half (t=0: h=0)
      bf16x8 z = (bf16x8){0,0,0,0,0,0,0,0};
      #pragma unroll
      for (int j = 0; j < 4; ++j)
        *(bf16x8*)&lA[xr_ * 512 + (32 + ((4 * xcb + j) ^ xk)) * 8] = z;
    }
    for (int t = 0; t < 6; ++t){
      // load this t's x chunk (4 x 16B per thread)
      bf16x8 xv[4];
      const u16* xp = xsrc + ((R + xr_) * 6 + t) * 256 + xcb * 32;
      #pragma unroll
      for (int j = 0; j < 4; ++j) xv[j] = *(const bf16x8*)(xp + j * 8);
      __syncthreads();                      // all frag reads of t-1 done
      #pragma unroll
      for (int mt = 0; mt < 2; ++mt)
        #pragma unroll
        for (int hf = 0; hf < 2; ++hf)
          #pragma unroll
          for (int nt = 0; nt < 8; ++nt)
            acc[mt][hf][nt] = (f32x4){0.f, 0.f, 0.f, 0.f};
      #pragma unroll
      for (int j = 0; j < 4; ++j)           // write x half (swizzled)
        *(bf16x8*)&lA[xr_ * 512 + ((4 * xcb + j) ^ xk) * 8] = xv[j];
      asm volatile("s_waitcnt lgkmcnt(0)" ::: "memory");
      __builtin_amdgcn_s_barrier();         // x + h visible to all waves

      // ---- K loop: 16 kt x 2 halves; B ring 2 ahead ----
#define HALF(HF)                                                               \
      {                                                                        \
        asm volatile("s_waitcnt vmcnt(8)" ::: "memory");                       \
        asm volatile("s_barrier" ::: "memory");                                \
        STB(g + 2);                                                            \
        const int ring = g % 3;                                                \
        bf16x8 af[2], bq[8];                                                   \
        _Pragma("unroll") for (int mt = 0; mt < 2; ++mt)                       \
          af[mt] = *(const bf16x8*)&lA[(mt * 16 + l15) * 512 +                 \
                                       ((ktc * 4 + lk) ^ ax) * 8];             \
        _Pragma("unroll") for (int nt = 0; nt < 8; ++nt)                       \
          bq[nt] = *(const bf16x8*)&lB[ring * 16384 +                          \
                     (wv * 64 + nt * 8 + (l15 >> 1)) * 64 + spB * 8];          \
        _Pragma("unroll") for (int mt = 0; mt < 2; ++mt)                       \
          _Pragma("unroll") for (int nt = 0; nt < 8; ++nt)                     \
            acc[mt][HF][nt] = __builtin_amdgcn_mfma_f32_16x16x32_bf16(         \
                af[mt], bq[nt], acc[mt][HF][nt], 0, 0, 0);                     \
        ++g;                                                                   \
      }
      for (int ktc = 0; ktc < 16; ++ktc){ HALF(0) HALF(1) }
#undef HALF

      // ---- cell update (verified quad-transpose) + h -> A h-half ----
      #pragma unroll
      for (int mt = 0; mt < 2; ++mt)
        #pragma unroll
        for (int hf = 0; hf < 2; ++hf)
          #pragma unroll
          for (int nt = 0; nt < 8; ++nt){
            const float bz = bv[hf][nt];
            float v0 = acc[mt][hf][nt][0] + bz;
            float v1 = acc[mt][hf][nt][1] + bz;
            float v2 = acc[mt][hf][nt][2] + bz;
            float v3 = acc[mt][hf][nt][3] + bz;
            float s0 = (a == 0) ? v0 : (a == 1) ? v1 : (a == 2) ? v2 : v3;
            float s1 = (a == 0) ? v1 : (a == 1) ? v2 : (a == 2) ? v3 : v0;
            float s2 = (a == 0) ? v2 : (a == 1) ? v3 : (a == 2) ? v0 : v1;
            float s3 = (a == 0) ? v3 : (a == 1) ? v0 : (a == 2) ? v1 : v2;
            float r0 = s0;
            float r1 = __shfl(s1, qb + ((a + 3) & 3));
            float r2 = __shfl(s2, qb + ((a + 2) & 3));
            float r3 = __shfl(s3, qb + ((a + 1) & 3));
            float wi = (a == 0) ? r0 : (a == 1) ? r1 : (a == 2) ? r2 : r3;
            float wf = (a == 1) ? r0 : (a == 2) ? r1 : (a == 3) ? r2 : r3;
            float wg = (a == 2) ? r0 : (a == 3) ? r1 : (a == 0) ? r2 : r3;
            float wo = (a == 3) ? r0 : (a == 0) ? r1 : (a == 1) ? r2 : r3;
            const int rloc = mt * 16 + lk * 4 + a;
            const int u    = hf * 128 + wv * 32 + nt * 4 + (l15 >> 2);
            float co = cc[mt][hf][nt];
            float ii = fsig(wi), ff = fsig(wf), gg = ftanh(wg), oo = fsig(wo);
            float cn = ff * co + ii * gg;
            float hn = oo * ftanh(cn);
            cc[mt][hf][nt] = cn;
            lA[rloc * 512 + (32 + ((u >> 3) ^ (rloc & 7))) * 8 + (u & 7)] = f2bf(hn);
          }
      asm volatile("s_waitcnt lgkmcnt(0)" ::: "memory");
      __builtin_amdgcn_s_barrier();         // h visible
      // bounce h -> global (next layer's x / final output)
      #pragma unroll
      for (int j = 0; j < 4; ++j){
        bf16x8 hv = *(const bf16x8*)&lA[xr_ * 512 + (32 + ((4 * xcb + j) ^ xk)) * 8];
        *(bf16x8*)(hdst + ((R + xr_) * 6 + t) * 256 + xcb * 32 + j * 8) = hv;
      }
    }
  }
}

// ---------- tail: viewport + score + mean ----------
__global__ void k_score(const u16* __restrict__ X3, const float* __restrict__ Wv,
                        const float* __restrict__ bv, const float* __restrict__ Ws,
                        const float* __restrict__ bs, float* __restrict__ score){
  int lane = threadIdx.x & 63;
  int bm = blockIdx.x * 4 + (threadIdx.x >> 6);
  const u16* row = X3 + (long)bm * (NVIEW * 256);
  float4 wv = *(const float4*)(Wv + lane * 4);
  float p = 0.f;
  #pragma unroll
  for (int n = 0; n < NVIEW; ++n){
    ushort4 xv = *(const ushort4*)(row + n * 256 + lane * 4);
    float d = bf2f(xv.x) * wv.x + bf2f(xv.y) * wv.y + bf2f(xv.z) * wv.z + bf2f(xv.w) * wv.w;
    p += Ws[n] * d;
  }
  #pragma unroll
  for (int off = 32; off; off >>= 1) p += __shfl_xor(p, off);
  if (lane == 0){
    float sw = Ws[0] + Ws[1] + Ws[2] + Ws[3] + Ws[4] + Ws[5];
    score[bm] = p + bv[0] * sw + bs[0];
  }
}

__global__ void k_mean(const float* __restrict__ score, float* __restrict__ out){
  __shared__ float red[256];
  int b = blockIdx.x, tid = threadIdx.x;
  red[tid] = score[b * 256 + tid];
  __syncthreads();
  for (int s = 128; s > 0; s >>= 1){
    if (tid < s) red[tid] += red[tid + s];
    __syncthreads();
  }
  if (tid == 0) out[b] = red[0] * (1.0f / 256.0f);
}

// ---------- launcher ----------
extern "C" void kernel_launch(void* const* d_in, const int* in_sizes, int n_in,
                              void* d_out, int out_size, void* d_ws, size_t ws_size,
                              hipStream_t stream){
  const float* swin = (const float*)d_in[0];
  const float* conv = (const float*)d_in[1];
  const float* Wc   = (const float*)d_in[2];
  const float* bc   = (const float*)d_in[3];
  const float* Win  = (const float*)d_in[4];
  const float* b_in = (const float*)d_in[5];
  const float* Wih  = (const float*)d_in[6];
  const float* Whh  = (const float*)d_in[7];
  const float* bih  = (const float*)d_in[8];
  const float* bhh  = (const float*)d_in[9];
  const float* Wv   = (const float*)d_in[10];
  const float* bv   = (const float*)d_in[11];
  const float* Ws   = (const float*)d_in[12];
  const float* bs   = (const float*)d_in[13];
  float* out = (float*)d_out;

  char* w = (char*)d_ws;
  u16*  convb = (u16*)(w);                    // conv bf16 [49152][1024]
  u16*  X0    = (u16*)(w);                    // reuses convb region after G1
  u16*  XA    = (u16*)(w + 25165824);
  u16*  XB    = (u16*)(w + 50331648);
  u16*  Y     = (u16*)(w + 100663296);        // [49152][1024] bf16
  u16*  Wcb   = (u16*)(w + 201326592);
  u16*  Winb  = (u16*)(w + 203423744);
  u16*  Wl    = (u16*)(w + 203948032);        // [3][1024][512] bf16
  float* biasL= (float*)(w + 207093760);
  float* scoreb = (float*)(w + 207106560);

  k_cvt<<<4096, 256, 0, stream>>>(conv, convb, 49152L * 1024 / 4);
  k_cvt<<<512, 256, 0, stream>>>(Wc, Wcb, 1048576 / 4);
  k_cvt<<<128, 256, 0, stream>>>(Win, Winb, 262144 / 4);
  k_build_wl<<<6144, 256, 0, stream>>>(Wih, Whh, Wl);
  k_build_bias<<<12, 256, 0, stream>>>(bih, bhh, biasL);

  // G1: Y = bf16( gelu(conv @ Wc^T + bc) + swin )   [49152 x 1024], NBn=8
  gemm_dr<0><<<3072, 256, 0, stream>>>(
      convb, 1024L, Wcb, 1024L, 1024, 1024, 8, bc, swin, Y);

  // G2: X0 = bf16( Y @ Win^T + b_in )               [49152 x 256], NBn=2
  gemm_dr<1><<<768, 256, 0, stream>>>(
      Y, 1024L, Winb, 1024L, 256, 1024, 2, b_in, (const float*)nullptr, X0);

  // Fused persistent LSTM (3 layers x 6 steps, one dispatch).
  // l0: x=X0 -> HA; l1: x=HA -> HB; l2: x=HB -> HA.
  k_lstm<<<256, 256, 0, stream>>>(X0, Wl, biasL, XA, XB);

  k_score<<<2048, 256, 0, stream>>>(XA, Wv, bv, Ws, bs, scoreb);
  k_mean<<<32, 256, 0, stream>>>(scoreb, out);
}

// Round 12
// 739.733 us; speedup vs baseline: 1.2864x; 1.2864x over previous
//
#include <hip/hip_runtime.h>
#include <math.h>
#include <stdint.h>

typedef unsigned short u16;
typedef float f32x4 __attribute__((ext_vector_type(4)));
typedef short bf16x8 __attribute__((ext_vector_type(8)));

#define NVIEW 6

// ---------- helpers ----------
__device__ __forceinline__ u16 f2bf(float f){
  unsigned u = __float_as_uint(f);
  u += 0x7FFFu + ((u >> 16) & 1u);
  return (u16)(u >> 16);
}
__device__ __forceinline__ float bf2f(u16 h){
  return __uint_as_float(((unsigned)h) << 16);
}
__device__ __forceinline__ float fsig(float x){
  x = fminf(fmaxf(x, -30.f), 30.f);
  return 1.0f / (1.0f + __expf(-x));
}
__device__ __forceinline__ float ftanh(float x){
  x = fminf(fmaxf(x, -15.f), 15.f);
  float e = __expf(2.0f * x);
  return (e - 1.0f) / (e + 1.0f);
}
__device__ __forceinline__ float gelu_exact(float v){
  float x  = v * 0.70710678118654752f;
  float ax = fabsf(x);
  float t  = 1.0f / fmaf(0.3275911f, ax, 1.0f);
  float p  = t * fmaf(t, fmaf(t, fmaf(t, fmaf(t, 1.061405429f, -1.453152027f),
                                      1.421413741f), -0.284496736f), 0.254829592f);
  float er = copysignf(1.0f - p * __expf(-ax * ax), x);
  return 0.5f * v * (1.0f + er);
}
__device__ __forceinline__ void gload16(const u16* g, u16* l){
  __builtin_amdgcn_global_load_lds((const __attribute__((address_space(1))) unsigned int*)g,
                                   (__attribute__((address_space(3))) unsigned int*)l,
                                   16, 0, 0);
}

#define DSRI(dst, addr, imm) \
  asm volatile("ds_read_b128 %0, %1 offset:%2" : "=v"(dst) : "v"(addr), "i"(imm))

// ---------- setup kernels ----------
__global__ void k_cvt(const float* __restrict__ in, u16* __restrict__ out, long n4){
  long i = (long)blockIdx.x * blockDim.x + threadIdx.x;
  long stride = (long)gridDim.x * blockDim.x;
  for (; i < n4; i += stride){
    const float4 v = ((const float4*)in)[i];
    ushort4 o;
    o.x = f2bf(v.x); o.y = f2bf(v.y); o.z = f2bf(v.z); o.w = f2bf(v.w);
    ((ushort4*)out)[i] = o;
  }
}

// Wl[l][4u+q][k] = (k<256 ? Wih[l][q*256+u][k] : Whh[l][q*256+u][k-256]) as bf16
__global__ void k_build_wl(const float* __restrict__ Wih, const float* __restrict__ Whh,
                           u16* __restrict__ Wl){
  int idx = blockIdx.x * 256 + threadIdx.x;
  int l   = idx >> 19;
  int rem = idx & 524287;
  int ro  = rem >> 9;
  int k   = rem & 511;
  int u = ro >> 2, q = ro & 3;
  int ri = q * 256 + u;
  float v = (k < 256) ? Wih[(l * 1024 + ri) * 256 + k]
                      : Whh[(l * 1024 + ri) * 256 + (k - 256)];
  Wl[idx] = f2bf(v);
}

__global__ void k_build_bias(const float* __restrict__ bih, const float* __restrict__ bhh,
                             float* __restrict__ biasL){
  int idx = blockIdx.x * 256 + threadIdx.x;
  if (idx < 3072){
    int l = idx >> 10; int ro = idx & 1023;
    int u = ro >> 2, q = ro & 3;
    int ri = q * 256 + u;
    biasL[idx] = bih[l * 1024 + ri] + bhh[l * 1024 + ri];
  }
}

// =====================================================================
// Deep-ring 128x128 GEMM (r7-proven) for G1/G2.
// =====================================================================
template<int EPI>
__global__ __launch_bounds__(256, 2)
void gemm_dr(const u16* __restrict__ A0, long sA0,
             const u16* __restrict__ Bm, long sB,
             int N, int K, int NBn,
             const float* __restrict__ bias,
             const float* __restrict__ resid,
             u16* __restrict__ outb)
{
  __shared__ __align__(16) u16 lA[5 * 4096];
  __shared__ __align__(16) u16 lB[5 * 4096];

  const int tid  = threadIdx.x;
  const int lane = tid & 63;
  const int wid  = tid >> 6;
  const int wm = wid >> 1, wn = wid & 1;
  const int l15 = lane & 15, lk = lane >> 4;

  const int nwg = gridDim.x;
  const int qx  = nwg >> 3;
  const int bb  = blockIdx.x;
  const int swz = (bb & 7) * qx + (bb >> 3);
  const long m0 = (long)(swz / NBn) * 128;
  const int  n0 = (swz % NBn) * 128;
  const int  NT = K >> 5;

  const int rA0 = tid >> 2;
  const int cA  = tid & 3;
  const int slog = (((rA0 & 1) << 2) | cA) ^ ((rA0 >> 1) & 7);
  const int srow = (rA0 & ~1) | (slog >> 2);
  const int scol = (slog & 3) << 3;
  const int ldst = rA0 * 32 + cA * 8;

  auto STAGE = [&](int slot, int t){
    const int kb = t << 5;
    const int so = slot * 4096;
    #pragma unroll
    for (int c = 0; c < 2; ++c){
      const int r  = c * 64 + srow;
      gload16(A0 + (m0 + r) * sA0 + (kb + scol), &lA[so + c * 2048 + ldst]);
    }
    #pragma unroll
    for (int c = 0; c < 2; ++c){
      const int r  = c * 64 + srow;
      gload16(Bm + (long)(n0 + r) * sB + (kb + scol), &lB[so + c * 2048 + ldst]);
    }
  };

  f32x4 acc[4][4];
  #pragma unroll
  for (int i = 0; i < 4; ++i)
    #pragma unroll
    for (int j = 0; j < 4; ++j)
      acc[i][j] = (f32x4){0.f, 0.f, 0.f, 0.f};

  const int spA = (((l15 & 1) << 2) | lk) ^ (l15 >> 1);
  const int rdA = (wm * 32 + (l15 >> 1)) * 64 + spA * 8;
  const int rdB = (wn * 32 + (l15 >> 1)) * 64 + spA * 8;

  auto COMPUTE = [&](int slot){
    const int so = slot * 4096;
    bf16x8 af[4], bq[4];
    #pragma unroll
    for (int mf = 0; mf < 4; ++mf)
      af[mf] = *(const bf16x8*)&lA[so + rdA + mf * 512];
    #pragma unroll
    for (int nf = 0; nf < 4; ++nf)
      bq[nf] = *(const bf16x8*)&lB[so + rdB + nf * 512];
    #pragma unroll
    for (int mf = 0; mf < 4; ++mf)
      #pragma unroll
      for (int nf = 0; nf < 4; ++nf)
        acc[mf][nf] = __builtin_amdgcn_mfma_f32_16x16x32_bf16(af[mf], bq[nf], acc[mf][nf], 0, 0, 0);
  };

  STAGE(0, 0); STAGE(1, 1); STAGE(2, 2); STAGE(3, 3);

  int sr = 0, sw = 4;
  for (int t = 0; t + 4 <= NT; ++t){
    asm volatile("s_waitcnt vmcnt(12)" ::: "memory");
    asm volatile("s_barrier" ::: "memory");
    if (t + 4 < NT){ STAGE(sw, t + 4); }
    COMPUTE(sr);
    sr = (sr == 4) ? 0 : sr + 1;
    sw = (sw == 4) ? 0 : sw + 1;
  }
  asm volatile("s_waitcnt vmcnt(8)" ::: "memory");
  asm volatile("s_barrier" ::: "memory");
  COMPUTE(sr); sr = (sr == 4) ? 0 : sr + 1;
  asm volatile("s_waitcnt vmcnt(4)" ::: "memory");
  asm volatile("s_barrier" ::: "memory");
  COMPUTE(sr); sr = (sr == 4) ? 0 : sr + 1;
  asm volatile("s_waitcnt vmcnt(0)" ::: "memory");
  asm volatile("s_barrier" ::: "memory");
  COMPUTE(sr);

  #pragma unroll
  for (int mf = 0; mf < 4; ++mf){
    #pragma unroll
    for (int nf = 0; nf < 4; ++nf){
      int  n    = n0 + wn * 64 + nf * 16 + l15;
      long mrow = m0 + wm * 64 + mf * 16 + lk * 4;
      float bz = bias[n];
      #pragma unroll
      for (int r = 0; r < 4; ++r){
        float v = acc[mf][nf][r] + bz;
        long off = (mrow + r) * N + n;
        if (EPI == 0) v = gelu_exact(v) + resid[off];
        outb[off] = f2bf(v);
      }
    }
  }
}

// =====================================================================
// Fused persistent LSTM v2: 3 layers x 6 timesteps, ONE dispatch.
// 256 blocks x 512 thr (8 waves = 2/SIMD); block owns 32 batch rows.
// Wave (wr,wc): rows wr*16..+15, gate-cols wc*128 within each 512-gate
// half (hf). acc[2][8] static (rule 20).
//  - K-ROTATION: block starts its (commutative) K accumulation at
//    ktc offset rotk=(blockIdx>>3)&15 -> the 32 CUs of an XCD stream
//    DIFFERENT Wl lines -> distinct-line L2 BW (fixes r11's same-line
//    serialization, 870 GB/s -> ~4 TB/s per XCD).
//  - B ring 3 x [512][32] (32 KB each); 4 gloads/thread/stage; counted
//    vmcnt(4) = 2-stage pipeline; per-t vmcnt(0) drain makes counts
//    exact (x-loads/h-stores excluded). r7 inverse-perm swizzle.
//  - A-LDS [32][512] (x half + h half), 16B-slot XOR swizzle; h written
//    in place by the cell update; barrier between last MFMA and the h
//    overwrite (fixes r11 race).
//  - asm ds_read + lgkm(0) + sched_barrier (rule 18) in the body.
// =====================================================================
__global__ __launch_bounds__(512, 2)
void k_lstm(const u16* __restrict__ X0, const u16* __restrict__ Wl,
            const float* __restrict__ biasL,
            u16* __restrict__ HA, u16* __restrict__ HB)
{
  __shared__ __align__(16) u16 lA[16384];      // [32][512] swizzled
  __shared__ __align__(16) u16 lB[3 * 16384];  // ring of [512][32]

  const int tid  = threadIdx.x;
  const int lane = tid & 63;
  const int wv   = tid >> 6;            // 0..7
  const int wr   = wv >> 2;             // row half (16 rows)
  const int wc   = wv & 3;              // gate col group (128 cols)
  const int l15  = lane & 15, lk = lane >> 4;
  const int axk  = l15 & 7;
  const int spB  = (((l15 & 1) << 2) | lk) ^ (l15 >> 1);
  const int a    = lane & 3;
  const int qb   = lane & ~3;
  const long R   = (long)blockIdx.x * 32;
  const int rotk = (blockIdx.x >> 3) & 15;

  // B staging mapping (512 threads, r7 inverse-perm)
  const int rB = tid >> 2;              // 0..127
  const int cB = tid & 3;
  const int slogB = (((rB & 1) << 2) | cB) ^ ((rB >> 1) & 7);
  const int srowB = (rB & ~1) | (slogB >> 2);
  const int scolB = (slogB & 3) << 3;
  const int ldstB = rB * 32 + cB * 8;

  auto STB = [&](int P, int l){
    const int hfp  = P & 1;
    const int ktcp = ((P >> 1) + rotk) & 15;
    const int slot = P % 3;
    const u16* src = Wl + (long)l * 524288 + (long)hfp * 262144 + ktcp * 32;
    u16* dst = &lB[slot * 16384];
    #pragma unroll
    for (int ch = 0; ch < 4; ++ch)
      gload16(src + (long)(ch * 128 + srowB) * 512 + scolB, dst + ch * 4096 + ldstB);
  };

  // x/h bounce mapping: 32 rows x 16 chunks of 16 u16 (2 slots each)
  const int xr_ = tid >> 4;
  const int xcb = tid & 15;
  const int xk  = xr_ & 7;

  const unsigned ldsA = (unsigned)(uintptr_t)&lA[0];
  const unsigned ldsB = (unsigned)(uintptr_t)&lB[0];
  const unsigned aRd  = ldsA + (unsigned)((wr * 16 + l15) * 1024);
  const unsigned bRd  = ldsB + (unsigned)((wc * 64 + (l15 >> 1)) * 128 + spB * 16);

  f32x4 acc[2][8];
  float cc[2][8];
  float bv[2][8];

  for (int l = 0; l < 3; ++l){
    const u16* xsrc = (l == 0) ? X0 : ((l == 1) ? HA : HB);
    u16* hdst = (l == 1) ? HB : HA;
    #pragma unroll
    for (int hf = 0; hf < 2; ++hf)
      #pragma unroll
      for (int nt = 0; nt < 8; ++nt){
        bv[hf][nt] = biasL[l * 1024 + hf * 512 + wc * 128 + nt * 16 + l15];
        cc[hf][nt] = 0.f;
      }
    __syncthreads();                       // prev layer fully done
    {                                      // zero h-half (t=0: h=0)
      bf16x8 z = (bf16x8){0,0,0,0,0,0,0,0};
      #pragma unroll
      for (int j = 0; j < 2; ++j){
        const int s = xcb * 2 + j;
        *(bf16x8*)&lA[xr_ * 512 + (32 + (s ^ xk)) * 8] = z;
      }
    }
    for (int t = 0; t < 6; ++t){
      // x chunk for this t (2 x b128)
      bf16x8 xv[2];
      const u16* xp = xsrc + ((R + xr_) * 6 + t) * 256 + xcb * 16;
      xv[0] = *(const bf16x8*)(xp);
      xv[1] = *(const bf16x8*)(xp + 8);
      asm volatile("s_waitcnt vmcnt(0)" ::: "memory");  // x in regs; stores drained
      #pragma unroll
      for (int hf = 0; hf < 2; ++hf)
        #pragma unroll
        for (int nt = 0; nt < 8; ++nt)
          acc[hf][nt] = (f32x4){0.f, 0.f, 0.f, 0.f};
      #pragma unroll
      for (int j = 0; j < 2; ++j){
        const int s = xcb * 2 + j;
        *(bf16x8*)&lA[xr_ * 512 + (s ^ xk) * 8] = xv[j];
      }
      STB(0, l); STB(1, l);
      asm volatile("s_waitcnt lgkmcnt(0)" ::: "memory");
      __builtin_amdgcn_s_barrier();        // x + h visible to all waves

      for (int j = 0; j < 16; ++j){
        const int ktc = (j + rotk) & 15;
        const unsigned aAddr = aRd + (unsigned)((((ktc * 4 + lk) ^ axk)) << 4);
        #pragma unroll
        for (int hh = 0; hh < 2; ++hh){
          const int P = 2 * j + hh;
          if (P == 31) { asm volatile("s_waitcnt vmcnt(0)" ::: "memory"); }
          else         { asm volatile("s_waitcnt vmcnt(4)" ::: "memory"); }
          __builtin_amdgcn_s_barrier();
          if (P + 2 < 32) STB(P + 2, l);
          bf16x8 af, bq[8];
          DSRI(af, aAddr, 0);
          const unsigned bAddr = bRd + (unsigned)((P % 3) * 32768);
          DSRI(bq[0], bAddr, 0);
          DSRI(bq[1], bAddr, 1024);
          DSRI(bq[2], bAddr, 2048);
          DSRI(bq[3], bAddr, 3072);
          DSRI(bq[4], bAddr, 4096);
          DSRI(bq[5], bAddr, 5120);
          DSRI(bq[6], bAddr, 6144);
          DSRI(bq[7], bAddr, 7168);
          asm volatile("s_waitcnt lgkmcnt(0)" ::: "memory");
          __builtin_amdgcn_sched_barrier(0);   // rule 18
          __builtin_amdgcn_s_setprio(1);
          #pragma unroll
          for (int nt = 0; nt < 8; ++nt)
            acc[hh][nt] = __builtin_amdgcn_mfma_f32_16x16x32_bf16(af, bq[nt], acc[hh][nt], 0, 0, 0);
          __builtin_amdgcn_s_setprio(0);
        }
      }
      __builtin_amdgcn_s_barrier();        // all waves' reads done (race fix)

      // ---- cell update (verified quad-transpose) + h -> A h-half ----
      #pragma unroll
      for (int hf = 0; hf < 2; ++hf)
        #pragma unroll
        for (int nt = 0; nt < 8; ++nt){
          const float bz = bv[hf][nt];
          float v0 = acc[hf][nt][0] + bz;
          float v1 = acc[hf][nt][1] + bz;
          float v2 = acc[hf][nt][2] + bz;
          float v3 = acc[hf][nt][3] + bz;
          float s0 = (a == 0) ? v0 : (a == 1) ? v1 : (a == 2) ? v2 : v3;
          float s1 = (a == 0) ? v1 : (a == 1) ? v2 : (a == 2) ? v3 : v0;
          float s2 = (a == 0) ? v2 : (a == 1) ? v3 : (a == 2) ? v0 : v1;
          float s3 = (a == 0) ? v3 : (a == 1) ? v0 : (a == 2) ? v1 : v2;
          float r0 = s0;
          float r1 = __shfl(s1, qb + ((a + 3) & 3));
          float r2 = __shfl(s2, qb + ((a + 2) & 3));
          float r3 = __shfl(s3, qb + ((a + 1) & 3));
          float wi = (a == 0) ? r0 : (a == 1) ? r1 : (a == 2) ? r2 : r3;
          float wf = (a == 1) ? r0 : (a == 2) ? r1 : (a == 3) ? r2 : r3;
          float wg = (a == 2) ? r0 : (a == 3) ? r1 : (a == 0) ? r2 : r3;
          float wo = (a == 3) ? r0 : (a == 0) ? r1 : (a == 1) ? r2 : r3;
          const int rloc = wr * 16 + lk * 4 + a;
          const int u    = hf * 128 + wc * 32 + nt * 4 + (l15 >> 2);
          float co = cc[hf][nt];
          float ii = fsig(wi), ff = fsig(wf), gg = ftanh(wg), oo = fsig(wo);
          float cn = ff * co + ii * gg;
          float hn = oo * ftanh(cn);
          cc[hf][nt] = cn;
          lA[rloc * 512 + (32 + ((u >> 3) ^ (rloc & 7))) * 8 + (u & 7)] = f2bf(hn);
        }
      asm volatile("s_waitcnt lgkmcnt(0)" ::: "memory");
      __builtin_amdgcn_s_barrier();        // h visible
      // bounce h -> global (next layer's x / final output)
      #pragma unroll
      for (int j2 = 0; j2 < 2; ++j2){
        const int s = xcb * 2 + j2;
        bf16x8 hv = *(const bf16x8*)&lA[xr_ * 512 + (32 + (s ^ xk)) * 8];
        *(bf16x8*)(hdst + ((R + xr_) * 6 + t) * 256 + xcb * 16 + j2 * 8) = hv;
      }
    }
  }
}

// ---------- tail: viewport + score + mean ----------
__global__ void k_score(const u16* __restrict__ X3, const float* __restrict__ Wv,
                        const float* __restrict__ bv, const float* __restrict__ Ws,
                        const float* __restrict__ bs, float* __restrict__ score){
  int lane = threadIdx.x & 63;
  int bm = blockIdx.x * 4 + (threadIdx.x >> 6);
  const u16* row = X3 + (long)bm * (NVIEW * 256);
  float4 wv = *(const float4*)(Wv + lane * 4);
  float p = 0.f;
  #pragma unroll
  for (int n = 0; n < NVIEW; ++n){
    ushort4 xv = *(const ushort4*)(row + n * 256 + lane * 4);
    float d = bf2f(xv.x) * wv.x + bf2f(xv.y) * wv.y + bf2f(xv.z) * wv.z + bf2f(xv.w) * wv.w;
    p += Ws[n] * d;
  }
  #pragma unroll
  for (int off = 32; off; off >>= 1) p += __shfl_xor(p, off);
  if (lane == 0){
    float sw = Ws[0] + Ws[1] + Ws[2] + Ws[3] + Ws[4] + Ws[5];
    score[bm] = p + bv[0] * sw + bs[0];
  }
}

__global__ void k_mean(const float* __restrict__ score, float* __restrict__ out){
  __shared__ float red[256];
  int b = blockIdx.x, tid = threadIdx.x;
  red[tid] = score[b * 256 + tid];
  __syncthreads();
  for (int s = 128; s > 0; s >>= 1){
    if (tid < s) red[tid] += red[tid + s];
    __syncthreads();
  }
  if (tid == 0) out[b] = red[0] * (1.0f / 256.0f);
}

// ---------- launcher ----------
extern "C" void kernel_launch(void* const* d_in, const int* in_sizes, int n_in,
                              void* d_out, int out_size, void* d_ws, size_t ws_size,
                              hipStream_t stream){
  const float* swin = (const float*)d_in[0];
  const float* conv = (const float*)d_in[1];
  const float* Wc   = (const float*)d_in[2];
  const float* bc   = (const float*)d_in[3];
  const float* Win  = (const float*)d_in[4];
  const float* b_in = (const float*)d_in[5];
  const float* Wih  = (const float*)d_in[6];
  const float* Whh  = (const float*)d_in[7];
  const float* bih  = (const float*)d_in[8];
  const float* bhh  = (const float*)d_in[9];
  const float* Wv   = (const float*)d_in[10];
  const float* bv   = (const float*)d_in[11];
  const float* Ws   = (const float*)d_in[12];
  const float* bs   = (const float*)d_in[13];
  float* out = (float*)d_out;

  char* w = (char*)d_ws;
  u16*  convb = (u16*)(w);
  u16*  X0    = (u16*)(w);
  u16*  XA    = (u16*)(w + 25165824);
  u16*  XB    = (u16*)(w + 50331648);
  u16*  Y     = (u16*)(w + 100663296);
  u16*  Wcb   = (u16*)(w + 201326592);
  u16*  Winb  = (u16*)(w + 203423744);
  u16*  Wl    = (u16*)(w + 203948032);
  float* biasL= (float*)(w + 207093760);
  float* scoreb = (float*)(w + 207106560);

  k_cvt<<<4096, 256, 0, stream>>>(conv, convb, 49152L * 1024 / 4);
  k_cvt<<<512, 256, 0, stream>>>(Wc, Wcb, 1048576 / 4);
  k_cvt<<<128, 256, 0, stream>>>(Win, Winb, 262144 / 4);
  k_build_wl<<<6144, 256, 0, stream>>>(Wih, Whh, Wl);
  k_build_bias<<<12, 256, 0, stream>>>(bih, bhh, biasL);

  // G1: Y = bf16( gelu(conv @ Wc^T + bc) + swin )   [49152 x 1024], NBn=8
  gemm_dr<0><<<3072, 256, 0, stream>>>(
      convb, 1024L, Wcb, 1024L, 1024, 1024, 8, bc, swin, Y);

  // G2: X0 = bf16( Y @ Win^T + b_in )               [49152 x 256], NBn=2
  gemm_dr<1><<<768, 256, 0, stream>>>(
      Y, 1024L, Winb, 1024L, 256, 1024, 2, b_in, (const float*)nullptr, X0);

  // Fused persistent LSTM v2 (rotation + 2/SIMD + counted ring).
  k_lstm<<<256, 512, 0, stream>>>(X0, Wl, biasL, XA, XB);

  k_score<<<2048, 256, 0, stream>>>(XA, Wv, bv, Ws, bs, scoreb);
  k_mean<<<32, 256, 0, stream>>>(scoreb, out);
}